// Round 1
// baseline (1581.296 us; speedup 1.0000x reference)
//
#include <hip/hip_runtime.h>
#include <stdint.h>
#include <stddef.h>

#define NV 768
#define HD 128
#define NROWS (NV*NV)   // 589824

typedef short bf16x8 __attribute__((ext_vector_type(8)));
typedef float f32x4 __attribute__((ext_vector_type(4)));

#define MFMA16 __builtin_amdgcn_mfma_f32_16x16x32_bf16

// f32 -> bf16 (round-to-nearest-even), branch-free
__device__ __forceinline__ short f2bf(float f){
  uint32_t u = __float_as_uint(f);
  u = (u + 0x7FFFu + ((u >> 16) & 1u)) >> 16;
  return (short)u;
}

// load 8 contiguous f32 and convert into one bf16x8 A/B fragment
__device__ __forceinline__ bf16x8 load_frag_f32(const float* __restrict__ p){
  const float4 a = *reinterpret_cast<const float4*>(p);
  const float4 b = *reinterpret_cast<const float4*>(p + 4);
  bf16x8 r;
  r[0]=f2bf(a.x); r[1]=f2bf(a.y); r[2]=f2bf(a.z); r[3]=f2bf(a.w);
  r[4]=f2bf(b.x); r[5]=f2bf(b.y); r[6]=f2bf(b.z); r[7]=f2bf(b.w);
  return r;
}

// Load full 128x128 W (row-major [g][h]) as B-fragments: B[k][n] = W[n][k].
// Lane holds B[kt*32 + 8*(l>>4) + e][nt*16 + (l&15)] = W[nt*16+c][kt*32+8*g4+e]
__device__ __forceinline__ void load_W(const float* __restrict__ W, int c, int g4,
                                       bf16x8 Wb[4][8]){
  #pragma unroll
  for (int kt = 0; kt < 4; ++kt)
    #pragma unroll
    for (int nt = 0; nt < 8; ++nt)
      Wb[kt][nt] = load_frag_f32(W + (nt*16 + c)*HD + kt*32 + g4*8);
}

// ---------------- K0: Vx = x@eV_w.T+b ; Ux = x@nU_w.T+b ; Vx2 = x@nV_w.T+b ---
__global__ void k_small(const float* __restrict__ x,
    const float* __restrict__ W0, const float* __restrict__ b0, float* __restrict__ o0,
    const float* __restrict__ W1, const float* __restrict__ b1, float* __restrict__ o1,
    const float* __restrict__ W2, const float* __restrict__ b2, float* __restrict__ o2){
  const int i = blockIdx.x;
  const int g = threadIdx.x;  // 128
  const float* W; const float* b; float* o;
  if (blockIdx.y == 0)      { W = W0; b = b0; o = o0; }
  else if (blockIdx.y == 1) { W = W1; b = b1; o = o1; }
  else                      { W = W2; b = b2; o = o2; }
  __shared__ float xs[HD];
  xs[g] = x[i*HD + g];
  __syncthreads();
  float acc = b[g];
  const float4* w4 = reinterpret_cast<const float4*>(W + g*HD);
  const float4* x4 = reinterpret_cast<const float4*>(xs);
  #pragma unroll 8
  for (int h4 = 0; h4 < 32; ++h4){
    float4 wv = w4[h4]; float4 xv = x4[h4];
    acc += wv.x*xv.x + wv.y*xv.y + wv.z*xv.z + wv.w*xv.w;
  }
  o[i*HD + g] = acc;
}

// ---------------- K1: channel stats of e_new (sum, sumsq) ------------------
__global__ void __launch_bounds__(256,2) k_stats(const float* __restrict__ e,
    const float* __restrict__ W, const float* __restrict__ bias,
    const float* __restrict__ Vx,
    float* __restrict__ chsum, float* __restrict__ chsq){
  const int lane = threadIdx.x & 63;
  const int wave = threadIdx.x >> 6;
  const int c = lane & 15, g4 = lane >> 4;

  bf16x8 Wb[4][8];
  load_W(W, c, g4, Wb);
  float bg[8];
  #pragma unroll
  for (int nt = 0; nt < 8; ++nt) bg[nt] = bias[nt*16 + c];

  float bsum[8], bsq[8];
  #pragma unroll
  for (int nt = 0; nt < 8; ++nt){ bsum[nt] = 0.f; bsq[nt] = 0.f; }

  const int row_base = blockIdx.x*256 + wave*64;
  for (int t = 0; t < 4; ++t){
    const int r0 = row_base + t*16;
    const int i  = r0 / NV;           // tile-uniform (768 % 16 == 0)
    const int j0 = r0 - i*NV;
    bf16x8 Af[4];
    const float* rp = e + (size_t)(r0 + c)*HD + g4*8;
    #pragma unroll
    for (int kt = 0; kt < 4; ++kt) Af[kt] = load_frag_f32(rp + kt*32);
    f32x4 acc[8] = {};
    #pragma unroll
    for (int kt = 0; kt < 4; ++kt)
      #pragma unroll
      for (int nt = 0; nt < 8; ++nt)
        acc[nt] = MFMA16(Af[kt], Wb[kt][nt], acc[nt], 0, 0, 0);
    #pragma unroll
    for (int nt = 0; nt < 8; ++nt){
      const int g = nt*16 + c;
      const float vi = Vx[i*HD + g];
      #pragma unroll
      for (int q = 0; q < 4; ++q){
        const int j = j0 + g4*4 + q;
        const float z = (acc[nt][q] + bg[nt]) * (vi + Vx[j*HD + g]);
        bsum[nt] += z; bsq[nt] += z*z;
      }
    }
  }
  #pragma unroll
  for (int nt = 0; nt < 8; ++nt){
    float s1 = bsum[nt], s2 = bsq[nt];
    s1 += __shfl_xor(s1, 16, 64); s1 += __shfl_xor(s1, 32, 64);
    s2 += __shfl_xor(s2, 16, 64); s2 += __shfl_xor(s2, 32, 64);
    if (lane < 16){
      atomicAdd(&chsum[nt*16 + lane], s1);
      atomicAdd(&chsq [nt*16 + lane], s2);
    }
  }
}

// ---------------- K1b: a_h = gamma_h * rsqrt(var_h + eps) ------------------
__global__ void k_coef(const float* __restrict__ chsum, const float* __restrict__ chsq,
                       const float* __restrict__ gamma, float* __restrict__ acoef){
  const int h = threadIdx.x;  // 128
  const float inv = 1.f / (float)NROWS;
  const float mean = chsum[h] * inv;
  const float var  = chsq[h] * inv - mean*mean;
  acoef[h] = gamma[h] * rsqrtf(var + 1e-5f);
}

// ---------------- K2: per-row softmax sums S[i,h], T[i,h] ------------------
__global__ void __launch_bounds__(256,2) k_rowsum(const float* __restrict__ e,
    const float* __restrict__ W, const float* __restrict__ bias,
    const float* __restrict__ Vx, const float* __restrict__ acoef,
    const float* __restrict__ Vx2,
    float* __restrict__ Sg, float* __restrict__ Tg){
  const int lane = threadIdx.x & 63;
  const int wave = threadIdx.x >> 6;
  const int c = lane & 15, g4 = lane >> 4;
  const int i = blockIdx.x;

  bf16x8 Wb[4][8];
  load_W(W, c, g4, Wb);
  float bg[8], ag[8], vi[8];
  #pragma unroll
  for (int nt = 0; nt < 8; ++nt){
    bg[nt] = bias[nt*16 + c];
    ag[nt] = acoef[nt*16 + c];
    vi[nt] = Vx[i*HD + nt*16 + c];
  }
  float Sa[8], Ta[8];
  #pragma unroll
  for (int nt = 0; nt < 8; ++nt){ Sa[nt] = 0.f; Ta[nt] = 0.f; }

  for (int t = wave; t < 48; t += 4){
    const int j0 = t*16;
    bf16x8 Af[4];
    const float* rp = e + (size_t)(i*NV + j0 + c)*HD + g4*8;
    #pragma unroll
    for (int kt = 0; kt < 4; ++kt) Af[kt] = load_frag_f32(rp + kt*32);
    f32x4 acc[8] = {};
    #pragma unroll
    for (int kt = 0; kt < 4; ++kt)
      #pragma unroll
      for (int nt = 0; nt < 8; ++nt)
        acc[nt] = MFMA16(Af[kt], Wb[kt][nt], acc[nt], 0, 0, 0);
    #pragma unroll
    for (int nt = 0; nt < 8; ++nt){
      const int g = nt*16 + c;
      #pragma unroll
      for (int q = 0; q < 4; ++q){
        const int j = j0 + g4*4 + q;
        const float z  = (acc[nt][q] + bg[nt]) * (vi[nt] + Vx[j*HD + g]);
        const float ex = __expf(ag[nt] * z);
        Sa[nt] += ex;
        Ta[nt] += ex * Vx2[j*HD + g];
      }
    }
  }
  __shared__ float ls[4][HD];
  __shared__ float lt[4][HD];
  #pragma unroll
  for (int nt = 0; nt < 8; ++nt){
    float s = Sa[nt], t2 = Ta[nt];
    s  += __shfl_xor(s , 16, 64); s  += __shfl_xor(s , 32, 64);
    t2 += __shfl_xor(t2, 16, 64); t2 += __shfl_xor(t2, 32, 64);
    if (lane < 16){ ls[wave][nt*16 + lane] = s; lt[wave][nt*16 + lane] = t2; }
  }
  __syncthreads();
  if (threadIdx.x < HD){
    const int h = threadIdx.x;
    Sg[i*HD + h] = ls[0][h] + ls[1][h] + ls[2][h] + ls[3][h];
    Tg[i*HD + h] = lt[0][h] + lt[1][h] + lt[2][h] + lt[3][h];
  }
}

// ---------------- K3: e_next = e * (1 + gate) ------------------------------
__global__ void __launch_bounds__(256,2) k_out(const float* __restrict__ e,
    const float* __restrict__ W, const float* __restrict__ bias,
    const float* __restrict__ Vx, const float* __restrict__ acoef,
    const float* __restrict__ Sg, float* __restrict__ oe){
  const int lane = threadIdx.x & 63;
  const int wave = threadIdx.x >> 6;
  const int c = lane & 15, g4 = lane >> 4;

  bf16x8 Wb[4][8];
  load_W(W, c, g4, Wb);
  float bg[8], ag[8];
  #pragma unroll
  for (int nt = 0; nt < 8; ++nt){
    bg[nt] = bias[nt*16 + c];
    ag[nt] = acoef[nt*16 + c];
  }
  const int row_base = blockIdx.x*256 + wave*64;
  for (int t = 0; t < 4; ++t){
    const int r0 = row_base + t*16;
    const int i  = r0 / NV;
    const int j0 = r0 - i*NV;
    bf16x8 Af[4];
    const float* rp = e + (size_t)(r0 + c)*HD + g4*8;
    #pragma unroll
    for (int kt = 0; kt < 4; ++kt) Af[kt] = load_frag_f32(rp + kt*32);
    f32x4 acc[8] = {};
    #pragma unroll
    for (int kt = 0; kt < 4; ++kt)
      #pragma unroll
      for (int nt = 0; nt < 8; ++nt)
        acc[nt] = MFMA16(Af[kt], Wb[kt][nt], acc[nt], 0, 0, 0);
    #pragma unroll
    for (int nt = 0; nt < 8; ++nt){
      const int g = nt*16 + c;
      const float vi   = Vx[i*HD + g];
      const float sinv = 1.f / Sg[i*HD + g];
      #pragma unroll
      for (int q = 0; q < 4; ++q){
        const int j = j0 + g4*4 + q;
        const int r = r0 + g4*4 + q;
        const float z    = (acc[nt][q] + bg[nt]) * (vi + Vx[j*HD + g]);
        const float gate = __expf(ag[nt] * z) * sinv;
        const size_t idx = (size_t)r*HD + g;
        const float ev = e[idx];       // L1-hot: wave just loaded this tile
        oe[idx] = ev + ev*gate;
      }
    }
  }
}

// ---------------- K4: x path (num/den, BN over nodes, relu, residual) ------
__global__ void k_x(const float* __restrict__ x, const float* __restrict__ Ux,
                    const float* __restrict__ Tg, const float* __restrict__ Sg,
                    const float* __restrict__ ngamma, const float* __restrict__ nbeta,
                    float* __restrict__ ox){
  const int ch = blockIdx.x;   // 128
  const int t  = threadIdx.x;  // 256
  float v[3]; float s1 = 0.f, s2 = 0.f;
  #pragma unroll
  for (int k = 0; k < 3; ++k){
    const int i = t + k*256;
    const float val = Ux[i*HD + ch] + Tg[i*HD + ch] / Sg[i*HD + ch]; // den = 1+1e-20
    v[k] = val; s1 += val; s2 += val*val;
  }
  __shared__ float r1[256], r2[256];
  r1[t] = s1; r2[t] = s2;
  __syncthreads();
  for (int off = 128; off > 0; off >>= 1){
    if (t < off){ r1[t] += r1[t+off]; r2[t] += r2[t+off]; }
    __syncthreads();
  }
  const float mu  = r1[0] * (1.f/768.f);
  const float var = r2[0] * (1.f/768.f) - mu*mu;
  const float sc = ngamma[ch] * rsqrtf(var + 1e-5f);
  const float sh = nbeta[ch] - mu*sc;
  #pragma unroll
  for (int k = 0; k < 3; ++k){
    const int i = t + k*256;
    const float bn = sc*v[k] + sh;
    ox[i*HD + ch] = x[i*HD + ch] + fmaxf(bn, 0.f);
  }
}

extern "C" void kernel_launch(void* const* d_in, const int* in_sizes, int n_in,
                              void* d_out, int out_size, void* d_ws, size_t ws_size,
                              hipStream_t stream){
  const float* x   = (const float*)d_in[0];
  const float* e   = (const float*)d_in[1];
  const float* eUw = (const float*)d_in[2];
  const float* eUb = (const float*)d_in[3];
  const float* eVw = (const float*)d_in[4];
  const float* eVb = (const float*)d_in[5];
  const float* nUw = (const float*)d_in[6];
  const float* nUb = (const float*)d_in[7];
  const float* nVw = (const float*)d_in[8];
  const float* nVb = (const float*)d_in[9];
  const float* eg  = (const float*)d_in[10];
  // d_in[11] = e_beta: drops out of the softmax, unused
  const float* ng  = (const float*)d_in[12];
  const float* nb  = (const float*)d_in[13];

  float* ws    = (float*)d_ws;
  float* chsum = ws;            // 128
  float* chsq  = ws + 128;      // 128
  float* acoef = ws + 256;      // 128
  float* Vx    = ws + 1024;     // 98304
  float* Ux    = Vx + 98304;
  float* Vx2   = Ux + 98304;
  float* Sg    = Vx2 + 98304;
  float* Tg    = Sg + 98304;

  float* out_x = (float*)d_out;          // 98304
  float* out_e = out_x + 98304;          // 75497472

  hipMemsetAsync(chsum, 0, 256*sizeof(float), stream);
  k_small<<<dim3(NV,3), 128, 0, stream>>>(x, eVw,eVb,Vx, nUw,nUb,Ux, nVw,nVb,Vx2);
  k_stats<<<2304, 256, 0, stream>>>(e, eUw, eUb, Vx, chsum, chsq);
  k_coef<<<1, 128, 0, stream>>>(chsum, chsq, eg, acoef);
  k_rowsum<<<NV, 256, 0, stream>>>(e, eUw, eUb, Vx, acoef, Vx2, Sg, Tg);
  k_out<<<2304, 256, 0, stream>>>(e, eUw, eUb, Vx, acoef, Sg, out_e);
  k_x<<<HD, 256, 0, stream>>>(x, Ux, Tg, Sg, ng, nb, out_x);
}